// Round 5
// baseline (2173.580 us; speedup 1.0000x reference)
//
#include <hip/hip_runtime.h>
#include <math.h>
#include <stdint.h>

// Problem constants
static constexpr int B_ = 128;
static constexpr int T_ = 64;
static constexpr int E_ = 2048;
static constexpr int H_ = 1024;
static constexpr int R_ = 8;
static constexpr int H3_ = 3 * H_;  // 3072

typedef unsigned short u16;
typedef __attribute__((ext_vector_type(4))) unsigned short u16x4;  // native vec (NT-load OK)
typedef __attribute__((ext_vector_type(8))) __bf16 bf16x8;
typedef __attribute__((ext_vector_type(4))) float f32x4;

__device__ __forceinline__ u16 f2bf(float f) {
    uint32_t x = __float_as_uint(f);
    x += 0x7fffu + ((x >> 16) & 1u);      // round-to-nearest-even
    return (u16)(x >> 16);
}
__device__ __forceinline__ float bf2f(u16 u) {
    return __uint_as_float(((uint32_t)u) << 16);
}

// async global->LDS, 16B per lane; LDS dest = wave-uniform base + lane*16
__device__ __forceinline__ void async_cp16(const u16* g, u16* l) {
    auto* g1 = (const __attribute__((address_space(1))) u16*)g;
    auto* l3 = (__attribute__((address_space(3))) u16*)(uintptr_t)l;
    __builtin_amdgcn_global_load_lds((const __attribute__((address_space(1))) void*)g1,
                                     (__attribute__((address_space(3))) void*)l3,
                                     16, 0, 0);
}

// ---------------------------------------------------------------------------
// LDS tiles use 128-byte rows (BK=64 bf16) with XOR swizzle:
//   phys_byte = (row*128 + col) ^ ((row & 7) << 4)
// global_load_lds writes linearly, so STAGE pre-applies the inverse (same)
// XOR on the global SOURCE column; fragment reads XOR the same mask.
// Measured R3: SQ_LDS_BANK_CONFLICT == 0 with this scheme.
// ---------------------------------------------------------------------------

__global__ __launch_bounds__(256) void zero_kernel(float* __restrict__ p, int n) {
    int i = blockIdx.x * 256 + threadIdx.x;
    if (i < n) p[i] = 0.0f;
}

// fp32 -> bf16 pack: dst[r*cols+c] = bf16(src[r*src_ld + col0 + c])
__global__ __launch_bounds__(256) void conv_bf(
    const float* __restrict__ src, int src_ld, int col0, int cols,
    u16* __restrict__ dst, int total4)
{
    int i4 = blockIdx.x * 256 + threadIdx.x;
    if (i4 >= total4) return;
    int i = i4 * 4;
    int r = i / cols, c = i - r * cols;
    const float4 v = *(const float4*)(src + (size_t)r * src_ld + col0 + c);
    ushort4 o;
    o.x = f2bf(v.x); o.y = f2bf(v.y); o.z = f2bf(v.z); o.w = f2bf(v.w);
    *(ushort4*)(dst + i) = o;
}

// ---------------------------------------------------------------------------
// Fused Phase 1 MFMA GEMM over all three weight sets.
// 128x128 tile, BK=64, swizzled LDS, double-buffered.
// grid ((B*Tc)/128, 72): x = m-block (fast axis -> resident W slice small),
// y -> which = y/24, n0 = (y%24)*128. GI stores are NON-TEMPORAL so the
// 75 MB/dispatch write stream does not evict W1 from L3 (R3: 221MB FETCH).
// ---------------------------------------------------------------------------
__global__ __launch_bounds__(256) void mfma_p1f(
    const u16* __restrict__ X, int t0, int tcshift,
    const u16* __restrict__ W1,
    const float* __restrict__ bs, const float* __restrict__ ba,
    const float* __restrict__ bo,
    u16* __restrict__ GI, size_t GI_elems)
{
    __shared__ u16 As[2][128 * 64];   // 16 KB each buf (swizzled 128B rows)
    __shared__ u16 Bs[2][128 * 64];   // total 64 KB exactly
    const int tid = threadIdx.x;
    const int m0 = blockIdx.x * 128;
    const int which = blockIdx.y / 24;
    const int n0 = (blockIdx.y % 24) * 128;
    const int tcmask = (1 << tcshift) - 1;

    const u16* W = W1 + (size_t)which * H3_ * E_;
    const float* bias = (which == 0) ? bs : (which == 1) ? ba : bo;
    u16* C = GI + (size_t)which * GI_elems;

    const int lane = tid & 63;
    const int wm = ((tid >> 6) & 1) * 64;
    const int wn = (tid >> 7) * 64;
    const int fr = lane & 15;            // fragment row (m for A, n for B)
    const int kq = (lane >> 4) * 8;      // k-quad elem offset
    const int ldsbase = (tid & 192) * 8; // wave-uniform LDS chunk base (elems)

    // staging geometry (round-invariant: rows advance by 32, multiple of 8)
    const int srow = tid >> 3;                                    // 0..31
    const int sce  = (((tid & 7) * 16) ^ ((srow & 7) << 4)) >> 1; // elem col

    f32x4 acc[4][4] = {};

    auto stage = [&](int buf, int k0) {
#pragma unroll
        for (int p = 0; p < 4; ++p) {
            int mrow = m0 + p * 32 + srow;
            int ro = ((mrow >> tcshift) * T_ + t0 + (mrow & tcmask)) * E_;
            async_cp16(X + ro + k0 + sce, &As[buf][p * 2048 + ldsbase]);
            int nrow = n0 + p * 32 + srow;
            async_cp16(W + (size_t)nrow * E_ + k0 + sce, &Bs[buf][p * 2048 + ldsbase]);
        }
    };
    auto compute = [&](int buf) {
#pragma unroll
        for (int kk = 0; kk < 2; ++kk) {
            bf16x8 a[4], b[4];
#pragma unroll
            for (int i = 0; i < 4; ++i) {
                int ra = wm + i * 16 + fr;
                int oa = (ra * 128 + kk * 64 + kq * 2) ^ ((ra & 7) << 4);
                a[i] = *(const bf16x8*)((const char*)&As[buf][0] + oa);
                int rb = wn + i * 16 + fr;
                int ob = (rb * 128 + kk * 64 + kq * 2) ^ ((rb & 7) << 4);
                b[i] = *(const bf16x8*)((const char*)&Bs[buf][0] + ob);
            }
#pragma unroll
            for (int mt = 0; mt < 4; ++mt)
#pragma unroll
                for (int nt = 0; nt < 4; ++nt)
                    acc[mt][nt] = __builtin_amdgcn_mfma_f32_16x16x32_bf16(
                        a[mt], b[nt], acc[mt][nt], 0, 0, 0);
        }
    };

    stage(0, 0);
    __syncthreads();                 // drains vmcnt: buf0 ready
    int cur = 0;
    for (int k0 = 64; k0 < E_; k0 += 64) {
        stage(cur ^ 1, k0);          // issue next-tile loads (overlap w/ compute)
        compute(cur);
        __syncthreads();             // next buf ready, cur free
        cur ^= 1;
    }
    compute(cur);

#pragma unroll
    for (int mt = 0; mt < 4; ++mt)
#pragma unroll
        for (int nt = 0; nt < 4; ++nt) {
            int n = n0 + wn + nt * 16 + fr;
            float bv = bias[n];
#pragma unroll
            for (int i = 0; i < 4; ++i) {
                int m = m0 + wm + mt * 16 + (lane >> 4) * 4 + i;
                __builtin_nontemporal_store(f2bf(acc[mt][nt][i] + bv),
                                            &C[(size_t)m * H3_ + n]);
            }
        }
}

// ---------------------------------------------------------------------------
// Per-step MFMA GEMM over gathered state rows. 128x64 tile, BK=64, swizzled,
// grid (48, 10) = 480 blocks, LDS 48KB -> 3 blocks/CU.
// XCD-aware remap: all 48 n-blocks of a row-group (sharing one 256KB A-panel
// and one W matrix) land on one XCD -> A-panel served from that XCD's L2.
// Bijective: groups 0..7 -> XCD g (48 slots); groups 8,9 split over XCD 0-3 /
// 4-7 (12 slots x 4). G layout [1280 x 3072] (rows of 128):
//   g=0 giS(Whsi) | g=1 ghS(Whs) | g=2 giA(Whai) | g=3 ghA(Wha) | g>=4 ghO(Who)
// ---------------------------------------------------------------------------
__global__ __launch_bounds__(256) void mfma_step(
    const u16* __restrict__ Abf, const int* __restrict__ dig, int t,
    const u16* __restrict__ Whsi, const u16* __restrict__ Whs,
    const u16* __restrict__ Whai, const u16* __restrict__ Wha,
    const u16* __restrict__ Who, float* __restrict__ G)
{
    __shared__ u16 As[2][128 * 64];  // 16 KB each buf
    __shared__ u16 Bs[2][64 * 64];   //  8 KB each buf
    __shared__ int rowoff[128];
    const int tid = threadIdx.x;

    // XCD-group remap (performance-only; any block->tile bijection is correct)
    const int wgid = blockIdx.y * 48 + blockIdx.x;
    const int xcd = wgid & 7;
    const int slot = wgid >> 3;           // 0..59
    int g, n0i;
    if (slot < 48) { g = xcd; n0i = slot; }
    else {
        int s = slot - 48;                // 0..11
        g = 8 + (xcd >> 2);
        n0i = s * 4 + (xcd & 3);
    }
    const int row0 = g * 128;
    const int n0 = n0i * 64;

    const u16* W;
    if      (g == 0) W = Whsi;
    else if (g == 1) W = Whs;
    else if (g == 2) W = Whai;
    else if (g == 3) W = Wha;
    else             W = Who;

    if (tid < 128) {
        int mo = row0 + tid;
        int b, role;
        if (mo < 512) {
            b = mo & 127;
            int kind = mo >> 7;
            int spk = dig[(b * T_ + t) * 2 + 0];
            int adr = dig[(b * T_ + t) * 2 + 1];
            role = (kind == 0 || kind == 3) ? adr : spk;
        } else {
            int o = mo - 512;
            b = o / 6;
            int j = o - b * 6;
            int spk = dig[(b * T_ + t) * 2 + 0];
            int adr = dig[(b * T_ + t) * 2 + 1];
            int cnt = 0; role = 0;
            for (int r = 0; r < R_; ++r) {
                if (r != spk && r != adr) {
                    if (cnt == j) { role = r; break; }
                    ++cnt;
                }
            }
        }
        rowoff[tid] = (b * R_ + role) * H_;
    }
    __syncthreads();

    const int lane = tid & 63;
    const int wid = tid >> 6;
    const int wm = (wid & 1) * 64;       // 2 waves along M (128)
    const int wn = (wid >> 1) * 32;      // 2 waves along N (64)
    const int fr = lane & 15;
    const int kq = (lane >> 4) * 8;
    const int ldsbase = (tid & 192) * 8;

    const int srow = tid >> 3;                                    // 0..31
    const int sce  = (((tid & 7) * 16) ^ ((srow & 7) << 4)) >> 1; // elem col

    f32x4 acc[4][2] = {};

    auto stage = [&](int buf, int k0) {
#pragma unroll
        for (int p = 0; p < 4; ++p) {    // A: 128 rows x 64 elems
            int r = p * 32 + srow;
            async_cp16(Abf + rowoff[r] + k0 + sce, &As[buf][p * 2048 + ldsbase]);
        }
#pragma unroll
        for (int p = 0; p < 2; ++p) {    // B: 64 rows x 64 elems
            int r = p * 32 + srow;
            async_cp16(W + (size_t)(n0 + r) * H_ + k0 + sce, &Bs[buf][p * 2048 + ldsbase]);
        }
    };
    auto compute = [&](int buf) {
#pragma unroll
        for (int kk = 0; kk < 2; ++kk) {
            bf16x8 a[4], b[2];
#pragma unroll
            for (int i = 0; i < 4; ++i) {
                int ra = wm + i * 16 + fr;
                int oa = (ra * 128 + kk * 64 + kq * 2) ^ ((ra & 7) << 4);
                a[i] = *(const bf16x8*)((const char*)&As[buf][0] + oa);
            }
#pragma unroll
            for (int j = 0; j < 2; ++j) {
                int rb = wn + j * 16 + fr;
                int ob = (rb * 128 + kk * 64 + kq * 2) ^ ((rb & 7) << 4);
                b[j] = *(const bf16x8*)((const char*)&Bs[buf][0] + ob);
            }
#pragma unroll
            for (int mt = 0; mt < 4; ++mt)
#pragma unroll
                for (int nt = 0; nt < 2; ++nt)
                    acc[mt][nt] = __builtin_amdgcn_mfma_f32_16x16x32_bf16(
                        a[mt], b[nt], acc[mt][nt], 0, 0, 0);
        }
    };

    stage(0, 0);
    __syncthreads();
    int cur = 0;
    for (int k0 = 64; k0 < H_; k0 += 64) {
        stage(cur ^ 1, k0);
        compute(cur);
        __syncthreads();
        cur ^= 1;
    }
    compute(cur);

#pragma unroll
    for (int mt = 0; mt < 4; ++mt)
#pragma unroll
        for (int nt = 0; nt < 2; ++nt) {
            int n = n0 + wn + nt * 16 + fr;
#pragma unroll
            for (int i = 0; i < 4; ++i) {
                int mo = row0 + wm + mt * 16 + (lane >> 4) * 4 + i;
                G[(size_t)mo * H3_ + n] = acc[mt][nt][i];
            }
        }
}

// ---------------------------------------------------------------------------
// Gate kernel. Block per (b, r), 4 elems/thread vectorized.
// ---------------------------------------------------------------------------
__global__ __launch_bounds__(256) void gate_kernel(
    const float* __restrict__ Aold, float* __restrict__ Anew,
    u16* __restrict__ Abf,
    const int* __restrict__ dig, int t, int tloc, int Tc,
    const u16* __restrict__ GIX, const u16* __restrict__ GIA,
    const u16* __restrict__ GIO, const float* __restrict__ G,
    const float* __restrict__ ws_bhh, const float* __restrict__ wa_bhh,
    const float* __restrict__ wo_bhh)
{
    const int blk = blockIdx.x;       // b*R + r
    const int b = blk >> 3, r = blk & 7;
    const int spk = dig[(b * T_ + t) * 2 + 0];
    const int adr = dig[(b * T_ + t) * 2 + 1];
    const size_t gi_row = (size_t)(b * Tc + tloc) * H3_;

    const u16* gi_pre;
    const float* gi_add;   // may be null (others)
    const float* gh;
    const float* bhh;
    if (r == spk) {
        gi_pre = GIX + gi_row;
        gi_add = G + (size_t)b * H3_;
        gh     = G + (size_t)(128 + b) * H3_;
        bhh    = ws_bhh;
    } else if (r == adr) {
        gi_pre = GIA + gi_row;
        gi_add = G + (size_t)(256 + b) * H3_;
        gh     = G + (size_t)(384 + b) * H3_;
        bhh    = wa_bhh;
    } else {
        int oidx = r - (spk < r ? 1 : 0) - (adr < r ? 1 : 0);
        gi_pre = GIO + gi_row;
        gi_add = nullptr;
        gh     = G + (size_t)(512 + b * 6 + oidx) * H3_;
        bhh    = wo_bhh;
    }

    const size_t hoff = (size_t)(b * R_ + r) * H_;
    const int i0 = threadIdx.x * 4;   // H_=1024, 256 thr, exactly 4 each
    float gir[4], giz[4], gin[4];
    {
        const u16x4 pr = __builtin_nontemporal_load((const u16x4*)(gi_pre + i0));
        const u16x4 pz = __builtin_nontemporal_load((const u16x4*)(gi_pre + H_ + i0));
        const u16x4 pn = __builtin_nontemporal_load((const u16x4*)(gi_pre + 2 * H_ + i0));
#pragma unroll
        for (int j = 0; j < 4; ++j) {
            gir[j] = bf2f(pr[j]);
            giz[j] = bf2f(pz[j]);
            gin[j] = bf2f(pn[j]);
        }
    }
    if (gi_add) {
        const float4 ar = *(const float4*)(gi_add + i0);
        const float4 az = *(const float4*)(gi_add + H_ + i0);
        const float4 an = *(const float4*)(gi_add + 2 * H_ + i0);
        gir[0] += ar.x; gir[1] += ar.y; gir[2] += ar.z; gir[3] += ar.w;
        giz[0] += az.x; giz[1] += az.y; giz[2] += az.z; giz[3] += az.w;
        gin[0] += an.x; gin[1] += an.y; gin[2] += an.z; gin[3] += an.w;
    }
    const float4 hr4 = *(const float4*)(gh + i0);
    const float4 hz4 = *(const float4*)(gh + H_ + i0);
    const float4 hn4 = *(const float4*)(gh + 2 * H_ + i0);
    const float4 br4 = *(const float4*)(bhh + i0);
    const float4 bz4 = *(const float4*)(bhh + H_ + i0);
    const float4 bn4 = *(const float4*)(bhh + 2 * H_ + i0);
    const float4 h4  = *(const float4*)(Aold + hoff + i0);

    float ghr[4] = {hr4.x + br4.x, hr4.y + br4.y, hr4.z + br4.z, hr4.w + br4.w};
    float ghz[4] = {hz4.x + bz4.x, hz4.y + bz4.y, hz4.z + bz4.z, hz4.w + bz4.w};
    float ghn[4] = {hn4.x + bn4.x, hn4.y + bn4.y, hn4.z + bn4.z, hn4.w + bn4.w};
    float hold[4] = {h4.x, h4.y, h4.z, h4.w};

    float4 o4;
    ushort4 ob4;
    float* op = &o4.x;
    u16* obp = &ob4.x;
#pragma unroll
    for (int j = 0; j < 4; ++j) {
        float rg = 1.0f / (1.0f + __expf(-(gir[j] + ghr[j])));
        float zg = 1.0f / (1.0f + __expf(-(giz[j] + ghz[j])));
        float ng = tanhf(gin[j] + rg * ghn[j]);
        float o  = (1.0f - zg) * ng + zg * hold[j];
        op[j] = o;
        obp[j] = f2bf(o);
    }
    *(float4*)(Anew + hoff + i0) = o4;
    *(ushort4*)(Abf + hoff + i0) = ob4;
}

// ---------------------------------------------------------------------------
extern "C" void kernel_launch(void* const* d_in, const int* in_sizes, int n_in,
                              void* d_out, int out_size, void* d_ws, size_t ws_size,
                              hipStream_t stream) {
    const float* enc    = (const float*)d_in[0];
    const int*   dig    = (const int*)d_in[1];
    const float* ws_ih  = (const float*)d_in[2];
    const float* ws_hh  = (const float*)d_in[3];
    const float* ws_bih = (const float*)d_in[4];
    const float* ws_bhh = (const float*)d_in[5];
    const float* wa_ih  = (const float*)d_in[6];
    const float* wa_hh  = (const float*)d_in[7];
    const float* wa_bih = (const float*)d_in[8];
    const float* wa_bhh = (const float*)d_in[9];
    const float* wo_ih  = (const float*)d_in[10];
    const float* wo_hh  = (const float*)d_in[11];
    const float* wo_bih = (const float*)d_in[12];
    const float* wo_bhh = (const float*)d_in[13];

    float* A0 = (float*)d_out;                    // (B, R, H) final output

    // ---- workspace layout (bytes) ----
    char* p = (char*)d_ws;
    auto take = [&](size_t bytes) { char* q = p; p += (bytes + 255) & ~(size_t)255; return q; };
    u16*   enc_bf = (u16*)  take((size_t)B_ * T_ * E_ * 2);          // 33.6 MB
    u16*   W1     = (u16*)  take((size_t)3 * H3_ * E_ * 2);          // 37.7 MB packed s|a|o
    u16*   W1s    = W1;
    u16*   W1a    = W1 + (size_t)H3_ * E_;
    u16*   W1o    = W1a + (size_t)H3_ * E_;
    u16*   Whsi   = (u16*)  take((size_t)H3_ * H_ * 2);              // 6.3 MB
    u16*   Whai   = (u16*)  take((size_t)H3_ * H_ * 2);
    u16*   Whs    = (u16*)  take((size_t)H3_ * H_ * 2);
    u16*   Wha    = (u16*)  take((size_t)H3_ * H_ * 2);
    u16*   Who    = (u16*)  take((size_t)H3_ * H_ * 2);
    u16*   Abf    = (u16*)  take((size_t)B_ * R_ * H_ * 2);          // 2 MB
    float* A1     = (float*)take((size_t)B_ * R_ * H_ * 4);          // 4 MB
    float* G      = (float*)take((size_t)1280 * H3_ * 4);            // 15.7 MB
    size_t fixed = (size_t)(p - (char*)d_ws);

    // chunk size: largest power-of-two Tc <= 64 fitting GI (3 sets, bf16)
    const size_t per_t = (size_t)3 * B_ * H3_ * 2;                   // 2.36 MB/step
    int Tc = 64;
    while (Tc > 1 && fixed + per_t * (size_t)Tc > ws_size) Tc >>= 1;
    int tcshift = 0;
    while ((1 << tcshift) < Tc) ++tcshift;
    const size_t GI_elems = (size_t)B_ * Tc * H3_;
    u16* GI  = (u16*)take(3 * GI_elems * 2);                         // packed X|A|O
    u16* GIX = GI;
    u16* GIA = GI + GI_elems;
    u16* GIO = GIA + GI_elems;

    dim3 blk(256);
    const size_t A_sz = (size_t)B_ * R_ * H_;

    // zero fp32 state (d_out) and bf16 state copy
    zero_kernel<<<dim3((int)((A_sz + 255) / 256)), blk, 0, stream>>>(A0, (int)A_sz);
    zero_kernel<<<dim3((int)((A_sz / 2 + 255) / 256)), blk, 0, stream>>>((float*)Abf, (int)(A_sz / 2));

    // ---- one-time bf16 conversions ----
    {
        int t4;
        t4 = B_ * T_ * E_ / 4;
        conv_bf<<<dim3((t4 + 255) / 256), blk, 0, stream>>>(enc, E_, 0, E_, enc_bf, t4);
        t4 = H3_ * E_ / 4;
        conv_bf<<<dim3((t4 + 255) / 256), blk, 0, stream>>>(ws_ih, E_ + H_, 0, E_, W1s, t4);
        conv_bf<<<dim3((t4 + 255) / 256), blk, 0, stream>>>(wa_ih, E_ + H_, 0, E_, W1a, t4);
        conv_bf<<<dim3((t4 + 255) / 256), blk, 0, stream>>>(wo_ih, E_, 0, E_, W1o, t4);
        t4 = H3_ * H_ / 4;
        conv_bf<<<dim3((t4 + 255) / 256), blk, 0, stream>>>(ws_ih, E_ + H_, E_, H_, Whsi, t4);
        conv_bf<<<dim3((t4 + 255) / 256), blk, 0, stream>>>(wa_ih, E_ + H_, E_, H_, Whai, t4);
        conv_bf<<<dim3((t4 + 255) / 256), blk, 0, stream>>>(ws_hh, H_, 0, H_, Whs, t4);
        conv_bf<<<dim3((t4 + 255) / 256), blk, 0, stream>>>(wa_hh, H_, 0, H_, Wha, t4);
        conv_bf<<<dim3((t4 + 255) / 256), blk, 0, stream>>>(wo_hh, H_, 0, H_, Who, t4);
    }

    float* Aold = A0;
    float* Anew = A1;
    for (int t0 = 0; t0 < T_; t0 += Tc) {
        // Phase 1 (chunk): all three input-side GEMMs fused in one dispatch.
        dim3 g1((B_ * Tc) / 128, 72);
        mfma_p1f<<<g1, blk, 0, stream>>>(enc_bf, t0, tcshift, W1,
                                         ws_bih, wa_bih, wo_bih, GI, GI_elems);

        // Phase 2: sequential recurrence within the chunk.
        for (int t = t0; t < t0 + Tc; ++t) {
            mfma_step<<<dim3(48, 10), blk, 0, stream>>>(
                Abf, dig, t, Whsi, Whs, Whai, Wha, Who, G);
            gate_kernel<<<dim3(B_ * R_), blk, 0, stream>>>(
                Aold, Anew, Abf, dig, t, t - t0, Tc, GIX, GIA, GIO, G,
                ws_bhh, wa_bhh, wo_bhh);
            float* tmp = Aold; Aold = Anew; Anew = tmp;
        }
    }
    // T_ = 64 total steps (even): final state lands in A0 == d_out.
}

// Round 6
// 2158.634 us; speedup vs baseline: 1.0069x; 1.0069x over previous
//
#include <hip/hip_runtime.h>
#include <math.h>
#include <stdint.h>

// Problem constants
static constexpr int B_ = 128;
static constexpr int T_ = 64;
static constexpr int E_ = 2048;
static constexpr int H_ = 1024;
static constexpr int R_ = 8;
static constexpr int H3_ = 3 * H_;  // 3072

typedef unsigned short u16;
typedef __attribute__((ext_vector_type(4))) unsigned short u16x4;  // native vec (NT-load OK)
typedef __attribute__((ext_vector_type(8))) __bf16 bf16x8;
typedef __attribute__((ext_vector_type(4))) float f32x4;

__device__ __forceinline__ u16 f2bf(float f) {
    uint32_t x = __float_as_uint(f);
    x += 0x7fffu + ((x >> 16) & 1u);      // round-to-nearest-even
    return (u16)(x >> 16);
}
__device__ __forceinline__ float bf2f(u16 u) {
    return __uint_as_float(((uint32_t)u) << 16);
}

// async global->LDS, 16B per lane; LDS dest = wave-uniform base + lane*16
__device__ __forceinline__ void async_cp16(const u16* g, u16* l) {
    auto* g1 = (const __attribute__((address_space(1))) u16*)g;
    auto* l3 = (__attribute__((address_space(3))) u16*)(uintptr_t)l;
    __builtin_amdgcn_global_load_lds((const __attribute__((address_space(1))) void*)g1,
                                     (__attribute__((address_space(3))) void*)l3,
                                     16, 0, 0);
}

// ---------------------------------------------------------------------------
// LDS tiles use 128-byte rows (BK=64 bf16) with XOR swizzle:
//   phys_byte = (row*128 + col) ^ ((row & 7) << 4)
// global_load_lds writes linearly, so STAGE pre-applies the inverse (same)
// XOR on the global SOURCE column; fragment reads XOR the same mask.
// Measured R3: SQ_LDS_BANK_CONFLICT == 0 with this scheme.
// ---------------------------------------------------------------------------

__global__ __launch_bounds__(256) void zero_kernel(float* __restrict__ p, int n) {
    int i = blockIdx.x * 256 + threadIdx.x;
    if (i < n) p[i] = 0.0f;
}

// fp32 -> bf16 pack: dst[r*cols+c] = bf16(src[r*src_ld + col0 + c])
__global__ __launch_bounds__(256) void conv_bf(
    const float* __restrict__ src, int src_ld, int col0, int cols,
    u16* __restrict__ dst, int total4)
{
    int i4 = blockIdx.x * 256 + threadIdx.x;
    if (i4 >= total4) return;
    int i = i4 * 4;
    int r = i / cols, c = i - r * cols;
    const float4 v = *(const float4*)(src + (size_t)r * src_ld + col0 + c);
    ushort4 o;
    o.x = f2bf(v.x); o.y = f2bf(v.y); o.z = f2bf(v.z); o.w = f2bf(v.w);
    *(ushort4*)(dst + i) = o;
}

// ---------------------------------------------------------------------------
// Fused Phase 1 MFMA GEMM over all three weight sets.
// 128x128 tile, BK=64, swizzled LDS, double-buffered.
// grid ((B*Tc)/128, 72): x = m-block, y -> which = y/24, n0 = (y%24)*128.
// Plain stores (R5: NT scalar stores doubled HBM writes via partial-line RMW).
// Measured R5: 814 TF = 33% dense peak (structural ceiling of 2-barrier loop).
// ---------------------------------------------------------------------------
__global__ __launch_bounds__(256) void mfma_p1f(
    const u16* __restrict__ X, int t0, int tcshift,
    const u16* __restrict__ W1,
    const float* __restrict__ bs, const float* __restrict__ ba,
    const float* __restrict__ bo,
    u16* __restrict__ GI, size_t GI_elems)
{
    __shared__ u16 As[2][128 * 64];   // 16 KB each buf (swizzled 128B rows)
    __shared__ u16 Bs[2][128 * 64];   // total 64 KB exactly
    const int tid = threadIdx.x;
    const int m0 = blockIdx.x * 128;
    const int which = blockIdx.y / 24;
    const int n0 = (blockIdx.y % 24) * 128;
    const int tcmask = (1 << tcshift) - 1;

    const u16* W = W1 + (size_t)which * H3_ * E_;
    const float* bias = (which == 0) ? bs : (which == 1) ? ba : bo;
    u16* C = GI + (size_t)which * GI_elems;

    const int lane = tid & 63;
    const int wm = ((tid >> 6) & 1) * 64;
    const int wn = (tid >> 7) * 64;
    const int fr = lane & 15;            // fragment row (m for A, n for B)
    const int kq = (lane >> 4) * 8;      // k-quad elem offset
    const int ldsbase = (tid & 192) * 8; // wave-uniform LDS chunk base (elems)

    // staging geometry (round-invariant: rows advance by 32, multiple of 8)
    const int srow = tid >> 3;                                    // 0..31
    const int sce  = (((tid & 7) * 16) ^ ((srow & 7) << 4)) >> 1; // elem col

    f32x4 acc[4][4] = {};

    auto stage = [&](int buf, int k0) {
#pragma unroll
        for (int p = 0; p < 4; ++p) {
            int mrow = m0 + p * 32 + srow;
            int ro = ((mrow >> tcshift) * T_ + t0 + (mrow & tcmask)) * E_;
            async_cp16(X + ro + k0 + sce, &As[buf][p * 2048 + ldsbase]);
            int nrow = n0 + p * 32 + srow;
            async_cp16(W + (size_t)nrow * E_ + k0 + sce, &Bs[buf][p * 2048 + ldsbase]);
        }
    };
    auto compute = [&](int buf) {
#pragma unroll
        for (int kk = 0; kk < 2; ++kk) {
            bf16x8 a[4], b[4];
#pragma unroll
            for (int i = 0; i < 4; ++i) {
                int ra = wm + i * 16 + fr;
                int oa = (ra * 128 + kk * 64 + kq * 2) ^ ((ra & 7) << 4);
                a[i] = *(const bf16x8*)((const char*)&As[buf][0] + oa);
                int rb = wn + i * 16 + fr;
                int ob = (rb * 128 + kk * 64 + kq * 2) ^ ((rb & 7) << 4);
                b[i] = *(const bf16x8*)((const char*)&Bs[buf][0] + ob);
            }
#pragma unroll
            for (int mt = 0; mt < 4; ++mt)
#pragma unroll
                for (int nt = 0; nt < 4; ++nt)
                    acc[mt][nt] = __builtin_amdgcn_mfma_f32_16x16x32_bf16(
                        a[mt], b[nt], acc[mt][nt], 0, 0, 0);
        }
    };

    stage(0, 0);
    __syncthreads();                 // drains vmcnt: buf0 ready
    int cur = 0;
    for (int k0 = 64; k0 < E_; k0 += 64) {
        stage(cur ^ 1, k0);          // issue next-tile loads (overlap w/ compute)
        compute(cur);
        __syncthreads();             // next buf ready, cur free
        cur ^= 1;
    }
    compute(cur);

#pragma unroll
    for (int mt = 0; mt < 4; ++mt)
#pragma unroll
        for (int nt = 0; nt < 4; ++nt) {
            int n = n0 + wn + nt * 16 + fr;
            float bv = bias[n];
#pragma unroll
            for (int i = 0; i < 4; ++i) {
                int m = m0 + wm + mt * 16 + (lane >> 4) * 4 + i;
                C[(size_t)m * H3_ + n] = f2bf(acc[mt][nt][i] + bv);
            }
        }
}

// ---------------------------------------------------------------------------
// Per-step MFMA GEMM over gathered state rows. 128x64 tile, BK=64, swizzled,
// grid (48, 10) = 480 blocks, LDS 48KB -> 3 blocks/CU.
// XCD remap v2 (R5 post-mortem): pin N-SLICES to XCDs, not row-groups.
// All 10 m-groups of n-slice s run on xcd = s%8. Per-XCD weight working set:
// 6 slices x 5 W-panels x 128KB = 3.75MB <= 4MB L2 -> weights stay L2-resident
// ACROSS ALL 64 STEPS (they never change). R4's g->XCD pinning pulled a full
// 6.3MB W per XCD (> L2) and thrashed every step.
// Bijection: xcd=wgid&7, idx=wgid>>3 (0..59), s=xcd+8*(idx/10), mg=idx%10.
// G layout [1280 x 3072] (m-groups of 128 rows):
//   mg=0 giS(Whsi) | mg=1 ghS(Whs) | mg=2 giA(Whai) | mg=3 ghA(Wha) | mg>=4 ghO(Who)
// ---------------------------------------------------------------------------
__global__ __launch_bounds__(256) void mfma_step(
    const u16* __restrict__ Abf, const int* __restrict__ dig, int t,
    const u16* __restrict__ Whsi, const u16* __restrict__ Whs,
    const u16* __restrict__ Whai, const u16* __restrict__ Wha,
    const u16* __restrict__ Who, float* __restrict__ G)
{
    __shared__ u16 As[2][128 * 64];  // 16 KB each buf
    __shared__ u16 Bs[2][64 * 64];   //  8 KB each buf
    __shared__ int rowoff[128];
    const int tid = threadIdx.x;

    // n-slice -> XCD pinned remap (performance-only; bijective)
    const int wgid = blockIdx.y * 48 + blockIdx.x;
    const int xcd = wgid & 7;
    const int idx = wgid >> 3;            // 0..59
    const int s   = xcd + 8 * (idx / 10); // n-slice 0..47
    const int mg  = idx % 10;             // m-group 0..9
    const int row0 = mg * 128;
    const int n0 = s * 64;

    const u16* W;
    if      (mg == 0) W = Whsi;
    else if (mg == 1) W = Whs;
    else if (mg == 2) W = Whai;
    else if (mg == 3) W = Wha;
    else              W = Who;

    if (tid < 128) {
        int mo = row0 + tid;
        int b, role;
        if (mo < 512) {
            b = mo & 127;
            int kind = mo >> 7;
            int spk = dig[(b * T_ + t) * 2 + 0];
            int adr = dig[(b * T_ + t) * 2 + 1];
            role = (kind == 0 || kind == 3) ? adr : spk;
        } else {
            int o = mo - 512;
            b = o / 6;
            int j = o - b * 6;
            int spk = dig[(b * T_ + t) * 2 + 0];
            int adr = dig[(b * T_ + t) * 2 + 1];
            int cnt = 0; role = 0;
            for (int r = 0; r < R_; ++r) {
                if (r != spk && r != adr) {
                    if (cnt == j) { role = r; break; }
                    ++cnt;
                }
            }
        }
        rowoff[tid] = (b * R_ + role) * H_;
    }
    __syncthreads();

    const int lane = tid & 63;
    const int wid = tid >> 6;
    const int wm = (wid & 1) * 64;       // 2 waves along M (128)
    const int wn = (wid >> 1) * 32;      // 2 waves along N (64)
    const int fr = lane & 15;
    const int kq = (lane >> 4) * 8;
    const int ldsbase = (tid & 192) * 8;

    const int srow = tid >> 3;                                    // 0..31
    const int sce  = (((tid & 7) * 16) ^ ((srow & 7) << 4)) >> 1; // elem col

    f32x4 acc[4][2] = {};

    auto stage = [&](int buf, int k0) {
#pragma unroll
        for (int p = 0; p < 4; ++p) {    // A: 128 rows x 64 elems
            int r = p * 32 + srow;
            async_cp16(Abf + rowoff[r] + k0 + sce, &As[buf][p * 2048 + ldsbase]);
        }
#pragma unroll
        for (int p = 0; p < 2; ++p) {    // B: 64 rows x 64 elems
            int r = p * 32 + srow;
            async_cp16(W + (size_t)(n0 + r) * H_ + k0 + sce, &Bs[buf][p * 2048 + ldsbase]);
        }
    };
    auto compute = [&](int buf) {
#pragma unroll
        for (int kk = 0; kk < 2; ++kk) {
            bf16x8 a[4], b[2];
#pragma unroll
            for (int i = 0; i < 4; ++i) {
                int ra = wm + i * 16 + fr;
                int oa = (ra * 128 + kk * 64 + kq * 2) ^ ((ra & 7) << 4);
                a[i] = *(const bf16x8*)((const char*)&As[buf][0] + oa);
            }
#pragma unroll
            for (int j = 0; j < 2; ++j) {
                int rb = wn + j * 16 + fr;
                int ob = (rb * 128 + kk * 64 + kq * 2) ^ ((rb & 7) << 4);
                b[j] = *(const bf16x8*)((const char*)&Bs[buf][0] + ob);
            }
#pragma unroll
            for (int mt = 0; mt < 4; ++mt)
#pragma unroll
                for (int nt = 0; nt < 2; ++nt)
                    acc[mt][nt] = __builtin_amdgcn_mfma_f32_16x16x32_bf16(
                        a[mt], b[nt], acc[mt][nt], 0, 0, 0);
        }
    };

    stage(0, 0);
    __syncthreads();
    int cur = 0;
    for (int k0 = 64; k0 < H_; k0 += 64) {
        stage(cur ^ 1, k0);
        compute(cur);
        __syncthreads();
        cur ^= 1;
    }
    compute(cur);

#pragma unroll
    for (int mt = 0; mt < 4; ++mt)
#pragma unroll
        for (int nt = 0; nt < 2; ++nt) {
            int n = n0 + wn + nt * 16 + fr;
#pragma unroll
            for (int i = 0; i < 4; ++i) {
                int mo = row0 + wm + mt * 16 + (lane >> 4) * 4 + i;
                G[(size_t)mo * H3_ + n] = acc[mt][nt][i];
            }
        }
}

// ---------------------------------------------------------------------------
// Gate kernel. Block per (b, r), 4 elems/thread vectorized.
// ---------------------------------------------------------------------------
__global__ __launch_bounds__(256) void gate_kernel(
    const float* __restrict__ Aold, float* __restrict__ Anew,
    u16* __restrict__ Abf,
    const int* __restrict__ dig, int t, int tloc, int Tc,
    const u16* __restrict__ GIX, const u16* __restrict__ GIA,
    const u16* __restrict__ GIO, const float* __restrict__ G,
    const float* __restrict__ ws_bhh, const float* __restrict__ wa_bhh,
    const float* __restrict__ wo_bhh)
{
    const int blk = blockIdx.x;       // b*R + r
    const int b = blk >> 3, r = blk & 7;
    const int spk = dig[(b * T_ + t) * 2 + 0];
    const int adr = dig[(b * T_ + t) * 2 + 1];
    const size_t gi_row = (size_t)(b * Tc + tloc) * H3_;

    const u16* gi_pre;
    const float* gi_add;   // may be null (others)
    const float* gh;
    const float* bhh;
    if (r == spk) {
        gi_pre = GIX + gi_row;
        gi_add = G + (size_t)b * H3_;
        gh     = G + (size_t)(128 + b) * H3_;
        bhh    = ws_bhh;
    } else if (r == adr) {
        gi_pre = GIA + gi_row;
        gi_add = G + (size_t)(256 + b) * H3_;
        gh     = G + (size_t)(384 + b) * H3_;
        bhh    = wa_bhh;
    } else {
        int oidx = r - (spk < r ? 1 : 0) - (adr < r ? 1 : 0);
        gi_pre = GIO + gi_row;
        gi_add = nullptr;
        gh     = G + (size_t)(512 + b * 6 + oidx) * H3_;
        bhh    = wo_bhh;
    }

    const size_t hoff = (size_t)(b * R_ + r) * H_;
    const int i0 = threadIdx.x * 4;   // H_=1024, 256 thr, exactly 4 each
    float gir[4], giz[4], gin[4];
    {
        const u16x4 pr = __builtin_nontemporal_load((const u16x4*)(gi_pre + i0));
        const u16x4 pz = __builtin_nontemporal_load((const u16x4*)(gi_pre + H_ + i0));
        const u16x4 pn = __builtin_nontemporal_load((const u16x4*)(gi_pre + 2 * H_ + i0));
#pragma unroll
        for (int j = 0; j < 4; ++j) {
            gir[j] = bf2f(pr[j]);
            giz[j] = bf2f(pz[j]);
            gin[j] = bf2f(pn[j]);
        }
    }
    if (gi_add) {
        const float4 ar = *(const float4*)(gi_add + i0);
        const float4 az = *(const float4*)(gi_add + H_ + i0);
        const float4 an = *(const float4*)(gi_add + 2 * H_ + i0);
        gir[0] += ar.x; gir[1] += ar.y; gir[2] += ar.z; gir[3] += ar.w;
        giz[0] += az.x; giz[1] += az.y; giz[2] += az.z; giz[3] += az.w;
        gin[0] += an.x; gin[1] += an.y; gin[2] += an.z; gin[3] += an.w;
    }
    const float4 hr4 = *(const float4*)(gh + i0);
    const float4 hz4 = *(const float4*)(gh + H_ + i0);
    const float4 hn4 = *(const float4*)(gh + 2 * H_ + i0);
    const float4 br4 = *(const float4*)(bhh + i0);
    const float4 bz4 = *(const float4*)(bhh + H_ + i0);
    const float4 bn4 = *(const float4*)(bhh + 2 * H_ + i0);
    const float4 h4  = *(const float4*)(Aold + hoff + i0);

    float ghr[4] = {hr4.x + br4.x, hr4.y + br4.y, hr4.z + br4.z, hr4.w + br4.w};
    float ghz[4] = {hz4.x + bz4.x, hz4.y + bz4.y, hz4.z + bz4.z, hz4.w + bz4.w};
    float ghn[4] = {hn4.x + bn4.x, hn4.y + bn4.y, hn4.z + bn4.z, hn4.w + bn4.w};
    float hold[4] = {h4.x, h4.y, h4.z, h4.w};

    float4 o4;
    ushort4 ob4;
    float* op = &o4.x;
    u16* obp = &ob4.x;
#pragma unroll
    for (int j = 0; j < 4; ++j) {
        float rg = 1.0f / (1.0f + __expf(-(gir[j] + ghr[j])));
        float zg = 1.0f / (1.0f + __expf(-(giz[j] + ghz[j])));
        float ng = tanhf(gin[j] + rg * ghn[j]);
        float o  = (1.0f - zg) * ng + zg * hold[j];
        op[j] = o;
        obp[j] = f2bf(o);
    }
    *(float4*)(Anew + hoff + i0) = o4;
    *(ushort4*)(Abf + hoff + i0) = ob4;
}

// ---------------------------------------------------------------------------
extern "C" void kernel_launch(void* const* d_in, const int* in_sizes, int n_in,
                              void* d_out, int out_size, void* d_ws, size_t ws_size,
                              hipStream_t stream) {
    const float* enc    = (const float*)d_in[0];
    const int*   dig    = (const int*)d_in[1];
    const float* ws_ih  = (const float*)d_in[2];
    const float* ws_hh  = (const float*)d_in[3];
    const float* ws_bih = (const float*)d_in[4];
    const float* ws_bhh = (const float*)d_in[5];
    const float* wa_ih  = (const float*)d_in[6];
    const float* wa_hh  = (const float*)d_in[7];
    const float* wa_bih = (const float*)d_in[8];
    const float* wa_bhh = (const float*)d_in[9];
    const float* wo_ih  = (const float*)d_in[10];
    const float* wo_hh  = (const float*)d_in[11];
    const float* wo_bih = (const float*)d_in[12];
    const float* wo_bhh = (const float*)d_in[13];

    float* A0 = (float*)d_out;                    // (B, R, H) final output

    // ---- workspace layout (bytes) ----
    char* p = (char*)d_ws;
    auto take = [&](size_t bytes) { char* q = p; p += (bytes + 255) & ~(size_t)255; return q; };
    u16*   enc_bf = (u16*)  take((size_t)B_ * T_ * E_ * 2);          // 33.6 MB
    u16*   W1     = (u16*)  take((size_t)3 * H3_ * E_ * 2);          // 37.7 MB packed s|a|o
    u16*   W1s    = W1;
    u16*   W1a    = W1 + (size_t)H3_ * E_;
    u16*   W1o    = W1a + (size_t)H3_ * E_;
    u16*   Whsi   = (u16*)  take((size_t)H3_ * H_ * 2);              // 6.3 MB
    u16*   Whai   = (u16*)  take((size_t)H3_ * H_ * 2);
    u16*   Whs    = (u16*)  take((size_t)H3_ * H_ * 2);
    u16*   Wha    = (u16*)  take((size_t)H3_ * H_ * 2);
    u16*   Who    = (u16*)  take((size_t)H3_ * H_ * 2);
    u16*   Abf    = (u16*)  take((size_t)B_ * R_ * H_ * 2);          // 2 MB
    float* A1     = (float*)take((size_t)B_ * R_ * H_ * 4);          // 4 MB
    float* G      = (float*)take((size_t)1280 * H3_ * 4);            // 15.7 MB
    size_t fixed = (size_t)(p - (char*)d_ws);

    // chunk size: largest power-of-two Tc <= 64 fitting GI (3 sets, bf16)
    const size_t per_t = (size_t)3 * B_ * H3_ * 2;                   // 2.36 MB/step
    int Tc = 64;
    while (Tc > 1 && fixed + per_t * (size_t)Tc > ws_size) Tc >>= 1;
    int tcshift = 0;
    while ((1 << tcshift) < Tc) ++tcshift;
    const size_t GI_elems = (size_t)B_ * Tc * H3_;
    u16* GI  = (u16*)take(3 * GI_elems * 2);                         // packed X|A|O
    u16* GIX = GI;
    u16* GIA = GI + GI_elems;
    u16* GIO = GIA + GI_elems;

    dim3 blk(256);
    const size_t A_sz = (size_t)B_ * R_ * H_;

    // zero fp32 state (d_out) and bf16 state copy
    zero_kernel<<<dim3((int)((A_sz + 255) / 256)), blk, 0, stream>>>(A0, (int)A_sz);
    zero_kernel<<<dim3((int)((A_sz / 2 + 255) / 256)), blk, 0, stream>>>((float*)Abf, (int)(A_sz / 2));

    // ---- one-time bf16 conversions ----
    {
        int t4;
        t4 = B_ * T_ * E_ / 4;
        conv_bf<<<dim3((t4 + 255) / 256), blk, 0, stream>>>(enc, E_, 0, E_, enc_bf, t4);
        t4 = H3_ * E_ / 4;
        conv_bf<<<dim3((t4 + 255) / 256), blk, 0, stream>>>(ws_ih, E_ + H_, 0, E_, W1s, t4);
        conv_bf<<<dim3((t4 + 255) / 256), blk, 0, stream>>>(wa_ih, E_ + H_, 0, E_, W1a, t4);
        conv_bf<<<dim3((t4 + 255) / 256), blk, 0, stream>>>(wo_ih, E_, 0, E_, W1o, t4);
        t4 = H3_ * H_ / 4;
        conv_bf<<<dim3((t4 + 255) / 256), blk, 0, stream>>>(ws_ih, E_ + H_, E_, H_, Whsi, t4);
        conv_bf<<<dim3((t4 + 255) / 256), blk, 0, stream>>>(wa_ih, E_ + H_, E_, H_, Whai, t4);
        conv_bf<<<dim3((t4 + 255) / 256), blk, 0, stream>>>(ws_hh, H_, 0, H_, Whs, t4);
        conv_bf<<<dim3((t4 + 255) / 256), blk, 0, stream>>>(wa_hh, H_, 0, H_, Wha, t4);
        conv_bf<<<dim3((t4 + 255) / 256), blk, 0, stream>>>(wo_hh, H_, 0, H_, Who, t4);
    }

    float* Aold = A0;
    float* Anew = A1;
    for (int t0 = 0; t0 < T_; t0 += Tc) {
        // Phase 1 (chunk): all three input-side GEMMs fused in one dispatch.
        dim3 g1((B_ * Tc) / 128, 72);
        mfma_p1f<<<g1, blk, 0, stream>>>(enc_bf, t0, tcshift, W1,
                                         ws_bih, wa_bih, wo_bih, GI, GI_elems);

        // Phase 2: sequential recurrence within the chunk.
        for (int t = t0; t < t0 + Tc; ++t) {
            mfma_step<<<dim3(48, 10), blk, 0, stream>>>(
                Abf, dig, t, Whsi, Whs, Whai, Wha, Who, G);
            gate_kernel<<<dim3(B_ * R_), blk, 0, stream>>>(
                Aold, Anew, Abf, dig, t, t - t0, Tc, GIX, GIA, GIO, G,
                ws_bhh, wa_bhh, wo_bhh);
            float* tmp = Aold; Aold = Anew; Anew = tmp;
        }
    }
    // T_ = 64 total steps (even): final state lands in A0 == d_out.
}

// Round 7
// 2085.853 us; speedup vs baseline: 1.0421x; 1.0349x over previous
//
#include <hip/hip_runtime.h>
#include <math.h>
#include <stdint.h>

// Problem constants
static constexpr int B_ = 128;
static constexpr int T_ = 64;
static constexpr int E_ = 2048;
static constexpr int H_ = 1024;
static constexpr int R_ = 8;
static constexpr int H3_ = 3 * H_;  // 3072

typedef unsigned short u16;
typedef __attribute__((ext_vector_type(4))) unsigned short u16x4;  // native vec (NT-load OK)
typedef __attribute__((ext_vector_type(8))) __bf16 bf16x8;
typedef __attribute__((ext_vector_type(4))) float f32x4;

__device__ __forceinline__ u16 f2bf(float f) {
    uint32_t x = __float_as_uint(f);
    x += 0x7fffu + ((x >> 16) & 1u);      // round-to-nearest-even
    return (u16)(x >> 16);
}
__device__ __forceinline__ float bf2f(u16 u) {
    return __uint_as_float(((uint32_t)u) << 16);
}

// async global->LDS, 16B per lane; LDS dest = wave-uniform base + lane*16
__device__ __forceinline__ void async_cp16(const u16* g, u16* l) {
    auto* g1 = (const __attribute__((address_space(1))) u16*)g;
    auto* l3 = (__attribute__((address_space(3))) u16*)(uintptr_t)l;
    __builtin_amdgcn_global_load_lds((const __attribute__((address_space(1))) void*)g1,
                                     (__attribute__((address_space(3))) void*)l3,
                                     16, 0, 0);
}

// counted waitcnt + full scheduling fence (rule #18: sched_barrier after asm wait)
#define WAIT_VM(N) do { asm volatile("s_waitcnt vmcnt(" #N ")" ::: "memory"); \
                        __builtin_amdgcn_sched_barrier(0); } while (0)

// ---------------------------------------------------------------------------
// LDS tiles use 128-byte rows (BK=64 bf16) with XOR swizzle:
//   phys_byte = (row*128 + col) ^ ((row & 7) << 4)
// global_load_lds writes linearly, so STAGE pre-applies the inverse (same)
// XOR on the global SOURCE column; fragment reads XOR the same mask.
// Measured R3: SQ_LDS_BANK_CONFLICT == 0 with this scheme.
// ---------------------------------------------------------------------------

__global__ __launch_bounds__(256) void zero_kernel(float* __restrict__ p, int n) {
    int i = blockIdx.x * 256 + threadIdx.x;
    if (i < n) p[i] = 0.0f;
}

// fp32 -> bf16 pack: dst[r*cols+c] = bf16(src[r*src_ld + col0 + c])
__global__ __launch_bounds__(256) void conv_bf(
    const float* __restrict__ src, int src_ld, int col0, int cols,
    u16* __restrict__ dst, int total4)
{
    int i4 = blockIdx.x * 256 + threadIdx.x;
    if (i4 >= total4) return;
    int i = i4 * 4;
    int r = i / cols, c = i - r * cols;
    const float4 v = *(const float4*)(src + (size_t)r * src_ld + col0 + c);
    ushort4 o;
    o.x = f2bf(v.x); o.y = f2bf(v.y); o.z = f2bf(v.z); o.w = f2bf(v.w);
    *(ushort4*)(dst + i) = o;
}

// ---------------------------------------------------------------------------
// Fused Phase 1 MFMA GEMM over all three weight sets.
// 128x128 tile, BK=64, swizzled LDS, double-buffered.
// grid ((B*Tc)/128, 72): x = m-block, y -> which = y/24, n0 = (y%24)*128.
// Measured R5/R6: 814 TF = 33% dense peak (2-barrier-loop structural ceiling).
// ---------------------------------------------------------------------------
__global__ __launch_bounds__(256) void mfma_p1f(
    const u16* __restrict__ X, int t0, int tcshift,
    const u16* __restrict__ W1,
    const float* __restrict__ bs, const float* __restrict__ ba,
    const float* __restrict__ bo,
    u16* __restrict__ GI, size_t GI_elems)
{
    __shared__ u16 As[2][128 * 64];   // 16 KB each buf (swizzled 128B rows)
    __shared__ u16 Bs[2][128 * 64];   // total 64 KB exactly
    const int tid = threadIdx.x;
    const int m0 = blockIdx.x * 128;
    const int which = blockIdx.y / 24;
    const int n0 = (blockIdx.y % 24) * 128;
    const int tcmask = (1 << tcshift) - 1;

    const u16* W = W1 + (size_t)which * H3_ * E_;
    const float* bias = (which == 0) ? bs : (which == 1) ? ba : bo;
    u16* C = GI + (size_t)which * GI_elems;

    const int lane = tid & 63;
    const int wm = ((tid >> 6) & 1) * 64;
    const int wn = (tid >> 7) * 64;
    const int fr = lane & 15;            // fragment row (m for A, n for B)
    const int kq = (lane >> 4) * 8;      // k-quad elem offset
    const int ldsbase = (tid & 192) * 8; // wave-uniform LDS chunk base (elems)

    // staging geometry (round-invariant: rows advance by 32, multiple of 8)
    const int srow = tid >> 3;                                    // 0..31
    const int sce  = (((tid & 7) * 16) ^ ((srow & 7) << 4)) >> 1; // elem col

    f32x4 acc[4][4] = {};

    auto stage = [&](int buf, int k0) {
#pragma unroll
        for (int p = 0; p < 4; ++p) {
            int mrow = m0 + p * 32 + srow;
            int ro = ((mrow >> tcshift) * T_ + t0 + (mrow & tcmask)) * E_;
            async_cp16(X + ro + k0 + sce, &As[buf][p * 2048 + ldsbase]);
            int nrow = n0 + p * 32 + srow;
            async_cp16(W + (size_t)nrow * E_ + k0 + sce, &Bs[buf][p * 2048 + ldsbase]);
        }
    };
    auto compute = [&](int buf) {
#pragma unroll
        for (int kk = 0; kk < 2; ++kk) {
            bf16x8 a[4], b[4];
#pragma unroll
            for (int i = 0; i < 4; ++i) {
                int ra = wm + i * 16 + fr;
                int oa = (ra * 128 + kk * 64 + kq * 2) ^ ((ra & 7) << 4);
                a[i] = *(const bf16x8*)((const char*)&As[buf][0] + oa);
                int rb = wn + i * 16 + fr;
                int ob = (rb * 128 + kk * 64 + kq * 2) ^ ((rb & 7) << 4);
                b[i] = *(const bf16x8*)((const char*)&Bs[buf][0] + ob);
            }
#pragma unroll
            for (int mt = 0; mt < 4; ++mt)
#pragma unroll
                for (int nt = 0; nt < 4; ++nt)
                    acc[mt][nt] = __builtin_amdgcn_mfma_f32_16x16x32_bf16(
                        a[mt], b[nt], acc[mt][nt], 0, 0, 0);
        }
    };

    stage(0, 0);
    __syncthreads();                 // drains vmcnt: buf0 ready
    int cur = 0;
    for (int k0 = 64; k0 < E_; k0 += 64) {
        stage(cur ^ 1, k0);          // issue next-tile loads (overlap w/ compute)
        compute(cur);
        __syncthreads();             // next buf ready, cur free
        cur ^= 1;
    }
    compute(cur);

#pragma unroll
    for (int mt = 0; mt < 4; ++mt)
#pragma unroll
        for (int nt = 0; nt < 4; ++nt) {
            int n = n0 + wn + nt * 16 + fr;
            float bv = bias[n];
#pragma unroll
            for (int i = 0; i < 4; ++i) {
                int m = m0 + wm + mt * 16 + (lane >> 4) * 4 + i;
                C[(size_t)m * H3_ + n] = f2bf(acc[mt][nt][i] + bv);
            }
        }
}

// ---------------------------------------------------------------------------
// Per-step MFMA GEMM over gathered state rows. 128x64 tile, BK=64, swizzled.
// grid (48, 10) = 480 blocks, LDS 72KB (3 bufs) -> 2 blocks/CU.
// R7: 3-buffer 2-DEEP prefetch with counted vmcnt(6) + raw s_barrier (T3/T4).
//   Per stage: 6 global_load_lds per thread (A:4, B:2). Steady state keeps 12
//   outstanding; vmcnt(6) completes exactly the stage needed next. The old
//   __syncthreads() drained vmcnt to 0 every iter -> each of 16 K-iters paid
//   the full cross-XCD A-gather latency (Abf rows just written by gate).
// Race audit: buf (t+2)%3 overwritten in iter t was read in iter t-1 BEFORE
// that iter's barrier (ds_read->MFMA dep completes reads); per-wave vmcnt
// before s_barrier => after barrier all waves' DMA chunks have landed.
// XCD remap v2 (R5): n-slices pinned to XCDs (neutral measured; kept).
// G layout [1280 x 3072] (m-groups of 128 rows):
//   mg=0 giS(Whsi) | mg=1 ghS(Whs) | mg=2 giA(Whai) | mg=3 ghA(Wha) | mg>=4 ghO(Who)
// ---------------------------------------------------------------------------
__global__ __launch_bounds__(256) void mfma_step(
    const u16* __restrict__ Abf, const int* __restrict__ dig, int t,
    const u16* __restrict__ Whsi, const u16* __restrict__ Whs,
    const u16* __restrict__ Whai, const u16* __restrict__ Wha,
    const u16* __restrict__ Who, float* __restrict__ G)
{
    __shared__ u16 As[3][128 * 64];  // 16 KB each buf
    __shared__ u16 Bs[3][64 * 64];   //  8 KB each buf
    __shared__ int rowoff[128];
    const int tid = threadIdx.x;

    // n-slice -> XCD pinned remap (performance-only; bijective)
    const int wgid = blockIdx.y * 48 + blockIdx.x;
    const int xcd = wgid & 7;
    const int idx = wgid >> 3;            // 0..59
    const int s   = xcd + 8 * (idx / 10); // n-slice 0..47
    const int mg  = idx % 10;             // m-group 0..9
    const int row0 = mg * 128;
    const int n0 = s * 64;

    const u16* W;
    if      (mg == 0) W = Whsi;
    else if (mg == 1) W = Whs;
    else if (mg == 2) W = Whai;
    else if (mg == 3) W = Wha;
    else              W = Who;

    if (tid < 128) {
        int mo = row0 + tid;
        int b, role;
        if (mo < 512) {
            b = mo & 127;
            int kind = mo >> 7;
            int spk = dig[(b * T_ + t) * 2 + 0];
            int adr = dig[(b * T_ + t) * 2 + 1];
            role = (kind == 0 || kind == 3) ? adr : spk;
        } else {
            int o = mo - 512;
            b = o / 6;
            int j = o - b * 6;
            int spk = dig[(b * T_ + t) * 2 + 0];
            int adr = dig[(b * T_ + t) * 2 + 1];
            int cnt = 0; role = 0;
            for (int r = 0; r < R_; ++r) {
                if (r != spk && r != adr) {
                    if (cnt == j) { role = r; break; }
                    ++cnt;
                }
            }
        }
        rowoff[tid] = (b * R_ + role) * H_;
    }
    __syncthreads();

    const int lane = tid & 63;
    const int wid = tid >> 6;
    const int wm = (wid & 1) * 64;       // 2 waves along M (128)
    const int wn = (wid >> 1) * 32;      // 2 waves along N (64)
    const int fr = lane & 15;
    const int kq = (lane >> 4) * 8;
    const int ldsbase = (tid & 192) * 8;

    const int srow = tid >> 3;                                    // 0..31
    const int sce  = (((tid & 7) * 16) ^ ((srow & 7) << 4)) >> 1; // elem col

    f32x4 acc[4][2] = {};

    auto stage = [&](int buf, int k0) {   // 6 loads/thread: A 4, B 2
#pragma unroll
        for (int p = 0; p < 4; ++p) {     // A: 128 rows x 64 elems
            int r = p * 32 + srow;
            async_cp16(Abf + rowoff[r] + k0 + sce, &As[buf][p * 2048 + ldsbase]);
        }
#pragma unroll
        for (int p = 0; p < 2; ++p) {     // B: 64 rows x 64 elems
            int r = p * 32 + srow;
            async_cp16(W + (size_t)(n0 + r) * H_ + k0 + sce, &Bs[buf][p * 2048 + ldsbase]);
        }
    };
    auto compute = [&](int buf) {
#pragma unroll
        for (int kk = 0; kk < 2; ++kk) {
            bf16x8 a[4], b[2];
#pragma unroll
            for (int i = 0; i < 4; ++i) {
                int ra = wm + i * 16 + fr;
                int oa = (ra * 128 + kk * 64 + kq * 2) ^ ((ra & 7) << 4);
                a[i] = *(const bf16x8*)((const char*)&As[buf][0] + oa);
            }
#pragma unroll
            for (int j = 0; j < 2; ++j) {
                int rb = wn + j * 16 + fr;
                int ob = (rb * 128 + kk * 64 + kq * 2) ^ ((rb & 7) << 4);
                b[j] = *(const bf16x8*)((const char*)&Bs[buf][0] + ob);
            }
#pragma unroll
            for (int mt = 0; mt < 4; ++mt)
#pragma unroll
                for (int nt = 0; nt < 2; ++nt)
                    acc[mt][nt] = __builtin_amdgcn_mfma_f32_16x16x32_bf16(
                        a[mt], b[nt], acc[mt][nt], 0, 0, 0);
        }
    };

    // ---- 2-deep pipeline over nk = 16 K-steps, buffers mod 3 ----
    stage(0, 0);                     // k-idx 0
    stage(1, 64);                    // k-idx 1; 12 outstanding
    WAIT_VM(6);                      // k-idx 0 landed (this wave)
    __builtin_amdgcn_s_barrier();    // all waves' k-idx 0 landed

    for (int t2 = 0; t2 < 14; ++t2) {
        stage((t2 + 2) % 3, (t2 + 2) * 64);   // 12 outstanding again
        compute(t2 % 3);
        WAIT_VM(6);                            // stage(t2+1) landed
        __builtin_amdgcn_s_barrier();
    }
    compute(14 % 3);                 // buf 2 (k-idx 14)
    WAIT_VM(0);                      // stage(15) landed
    __builtin_amdgcn_s_barrier();
    compute(15 % 3);                 // buf 0 (k-idx 15)

#pragma unroll
    for (int mt = 0; mt < 4; ++mt)
#pragma unroll
        for (int nt = 0; nt < 2; ++nt) {
            int n = n0 + wn + nt * 16 + fr;
#pragma unroll
            for (int i = 0; i < 4; ++i) {
                int mo = row0 + wm + mt * 16 + (lane >> 4) * 4 + i;
                G[(size_t)mo * H3_ + n] = acc[mt][nt][i];
            }
        }
}

// ---------------------------------------------------------------------------
// Gate kernel. Block per (b, r), 4 elems/thread vectorized.
// ---------------------------------------------------------------------------
__global__ __launch_bounds__(256) void gate_kernel(
    const float* __restrict__ Aold, float* __restrict__ Anew,
    u16* __restrict__ Abf,
    const int* __restrict__ dig, int t, int tloc, int Tc,
    const u16* __restrict__ GIX, const u16* __restrict__ GIA,
    const u16* __restrict__ GIO, const float* __restrict__ G,
    const float* __restrict__ ws_bhh, const float* __restrict__ wa_bhh,
    const float* __restrict__ wo_bhh)
{
    const int blk = blockIdx.x;       // b*R + r
    const int b = blk >> 3, r = blk & 7;
    const int spk = dig[(b * T_ + t) * 2 + 0];
    const int adr = dig[(b * T_ + t) * 2 + 1];
    const size_t gi_row = (size_t)(b * Tc + tloc) * H3_;

    const u16* gi_pre;
    const float* gi_add;   // may be null (others)
    const float* gh;
    const float* bhh;
    if (r == spk) {
        gi_pre = GIX + gi_row;
        gi_add = G + (size_t)b * H3_;
        gh     = G + (size_t)(128 + b) * H3_;
        bhh    = ws_bhh;
    } else if (r == adr) {
        gi_pre = GIA + gi_row;
        gi_add = G + (size_t)(256 + b) * H3_;
        gh     = G + (size_t)(384 + b) * H3_;
        bhh    = wa_bhh;
    } else {
        int oidx = r - (spk < r ? 1 : 0) - (adr < r ? 1 : 0);
        gi_pre = GIO + gi_row;
        gi_add = nullptr;
        gh     = G + (size_t)(512 + b * 6 + oidx) * H3_;
        bhh    = wo_bhh;
    }

    const size_t hoff = (size_t)(b * R_ + r) * H_;
    const int i0 = threadIdx.x * 4;   // H_=1024, 256 thr, exactly 4 each
    float gir[4], giz[4], gin[4];
    {
        const u16x4 pr = __builtin_nontemporal_load((const u16x4*)(gi_pre + i0));
        const u16x4 pz = __builtin_nontemporal_load((const u16x4*)(gi_pre + H_ + i0));
        const u16x4 pn = __builtin_nontemporal_load((const u16x4*)(gi_pre + 2 * H_ + i0));
#pragma unroll
        for (int j = 0; j < 4; ++j) {
            gir[j] = bf2f(pr[j]);
            giz[j] = bf2f(pz[j]);
            gin[j] = bf2f(pn[j]);
        }
    }
    if (gi_add) {
        const float4 ar = *(const float4*)(gi_add + i0);
        const float4 az = *(const float4*)(gi_add + H_ + i0);
        const float4 an = *(const float4*)(gi_add + 2 * H_ + i0);
        gir[0] += ar.x; gir[1] += ar.y; gir[2] += ar.z; gir[3] += ar.w;
        giz[0] += az.x; giz[1] += az.y; giz[2] += az.z; giz[3] += az.w;
        gin[0] += an.x; gin[1] += an.y; gin[2] += an.z; gin[3] += an.w;
    }
    const float4 hr4 = *(const float4*)(gh + i0);
    const float4 hz4 = *(const float4*)(gh + H_ + i0);
    const float4 hn4 = *(const float4*)(gh + 2 * H_ + i0);
    const float4 br4 = *(const float4*)(bhh + i0);
    const float4 bz4 = *(const float4*)(bhh + H_ + i0);
    const float4 bn4 = *(const float4*)(bhh + 2 * H_ + i0);
    const float4 h4  = *(const float4*)(Aold + hoff + i0);

    float ghr[4] = {hr4.x + br4.x, hr4.y + br4.y, hr4.z + br4.z, hr4.w + br4.w};
    float ghz[4] = {hz4.x + bz4.x, hz4.y + bz4.y, hz4.z + bz4.z, hz4.w + bz4.w};
    float ghn[4] = {hn4.x + bn4.x, hn4.y + bn4.y, hn4.z + bn4.z, hn4.w + bn4.w};
    float hold[4] = {h4.x, h4.y, h4.z, h4.w};

    float4 o4;
    ushort4 ob4;
    float* op = &o4.x;
    u16* obp = &ob4.x;
#pragma unroll
    for (int j = 0; j < 4; ++j) {
        float rg = 1.0f / (1.0f + __expf(-(gir[j] + ghr[j])));
        float zg = 1.0f / (1.0f + __expf(-(giz[j] + ghz[j])));
        float ng = tanhf(gin[j] + rg * ghn[j]);
        float o  = (1.0f - zg) * ng + zg * hold[j];
        op[j] = o;
        obp[j] = f2bf(o);
    }
    *(float4*)(Anew + hoff + i0) = o4;
    *(ushort4*)(Abf + hoff + i0) = ob4;
}

// ---------------------------------------------------------------------------
extern "C" void kernel_launch(void* const* d_in, const int* in_sizes, int n_in,
                              void* d_out, int out_size, void* d_ws, size_t ws_size,
                              hipStream_t stream) {
    const float* enc    = (const float*)d_in[0];
    const int*   dig    = (const int*)d_in[1];
    const float* ws_ih  = (const float*)d_in[2];
    const float* ws_hh  = (const float*)d_in[3];
    const float* ws_bih = (const float*)d_in[4];
    const float* ws_bhh = (const float*)d_in[5];
    const float* wa_ih  = (const float*)d_in[6];
    const float* wa_hh  = (const float*)d_in[7];
    const float* wa_bih = (const float*)d_in[8];
    const float* wa_bhh = (const float*)d_in[9];
    const float* wo_ih  = (const float*)d_in[10];
    const float* wo_hh  = (const float*)d_in[11];
    const float* wo_bih = (const float*)d_in[12];
    const float* wo_bhh = (const float*)d_in[13];

    float* A0 = (float*)d_out;                    // (B, R, H) final output

    // ---- workspace layout (bytes) ----
    char* p = (char*)d_ws;
    auto take = [&](size_t bytes) { char* q = p; p += (bytes + 255) & ~(size_t)255; return q; };
    u16*   enc_bf = (u16*)  take((size_t)B_ * T_ * E_ * 2);          // 33.6 MB
    u16*   W1     = (u16*)  take((size_t)3 * H3_ * E_ * 2);          // 37.7 MB packed s|a|o
    u16*   W1s    = W1;
    u16*   W1a    = W1 + (size_t)H3_ * E_;
    u16*   W1o    = W1a + (size_t)H3_ * E_;
    u16*   Whsi   = (u16*)  take((size_t)H3_ * H_ * 2);              // 6.3 MB
    u16*   Whai   = (u16*)  take((size_t)H3_ * H_ * 2);
    u16*   Whs    = (u16*)  take((size_t)H3_ * H_ * 2);
    u16*   Wha    = (u16*)  take((size_t)H3_ * H_ * 2);
    u16*   Who    = (u16*)  take((size_t)H3_ * H_ * 2);
    u16*   Abf    = (u16*)  take((size_t)B_ * R_ * H_ * 2);          // 2 MB
    float* A1     = (float*)take((size_t)B_ * R_ * H_ * 4);          // 4 MB
    float* G      = (float*)take((size_t)1280 * H3_ * 4);            // 15.7 MB
    size_t fixed = (size_t)(p - (char*)d_ws);

    // chunk size: largest power-of-two Tc <= 64 fitting GI (3 sets, bf16)
    const size_t per_t = (size_t)3 * B_ * H3_ * 2;                   // 2.36 MB/step
    int Tc = 64;
    while (Tc > 1 && fixed + per_t * (size_t)Tc > ws_size) Tc >>= 1;
    int tcshift = 0;
    while ((1 << tcshift) < Tc) ++tcshift;
    const size_t GI_elems = (size_t)B_ * Tc * H3_;
    u16* GI  = (u16*)take(3 * GI_elems * 2);                         // packed X|A|O
    u16* GIX = GI;
    u16* GIA = GI + GI_elems;
    u16* GIO = GIA + GI_elems;

    dim3 blk(256);
    const size_t A_sz = (size_t)B_ * R_ * H_;

    // zero fp32 state (d_out) and bf16 state copy
    zero_kernel<<<dim3((int)((A_sz + 255) / 256)), blk, 0, stream>>>(A0, (int)A_sz);
    zero_kernel<<<dim3((int)((A_sz / 2 + 255) / 256)), blk, 0, stream>>>((float*)Abf, (int)(A_sz / 2));

    // ---- one-time bf16 conversions ----
    {
        int t4;
        t4 = B_ * T_ * E_ / 4;
        conv_bf<<<dim3((t4 + 255) / 256), blk, 0, stream>>>(enc, E_, 0, E_, enc_bf, t4);
        t4 = H3_ * E_ / 4;
        conv_bf<<<dim3((t4 + 255) / 256), blk, 0, stream>>>(ws_ih, E_ + H_, 0, E_, W1s, t4);
        conv_bf<<<dim3((t4 + 255) / 256), blk, 0, stream>>>(wa_ih, E_ + H_, 0, E_, W1a, t4);
        conv_bf<<<dim3((t4 + 255) / 256), blk, 0, stream>>>(wo_ih, E_, 0, E_, W1o, t4);
        t4 = H3_ * H_ / 4;
        conv_bf<<<dim3((t4 + 255) / 256), blk, 0, stream>>>(ws_ih, E_ + H_, E_, H_, Whsi, t4);
        conv_bf<<<dim3((t4 + 255) / 256), blk, 0, stream>>>(wa_ih, E_ + H_, E_, H_, Whai, t4);
        conv_bf<<<dim3((t4 + 255) / 256), blk, 0, stream>>>(ws_hh, H_, 0, H_, Whs, t4);
        conv_bf<<<dim3((t4 + 255) / 256), blk, 0, stream>>>(wa_hh, H_, 0, H_, Wha, t4);
        conv_bf<<<dim3((t4 + 255) / 256), blk, 0, stream>>>(wo_hh, H_, 0, H_, Who, t4);
    }

    float* Aold = A0;
    float* Anew = A1;
    for (int t0 = 0; t0 < T_; t0 += Tc) {
        // Phase 1 (chunk): all three input-side GEMMs fused in one dispatch.
        dim3 g1((B_ * Tc) / 128, 72);
        mfma_p1f<<<g1, blk, 0, stream>>>(enc_bf, t0, tcshift, W1,
                                         ws_bih, wa_bih, wo_bih, GI, GI_elems);

        // Phase 2: sequential recurrence within the chunk.
        for (int t = t0; t < t0 + Tc; ++t) {
            mfma_step<<<dim3(48, 10), blk, 0, stream>>>(
                Abf, dig, t, Whsi, Whs, Whai, Wha, Who, G);
            gate_kernel<<<dim3(B_ * R_), blk, 0, stream>>>(
                Aold, Anew, Abf, dig, t, t - t0, Tc, GIX, GIA, GIO, G,
                ws_bhh, wa_bhh, wo_bhh);
            float* tmp = Aold; Aold = Anew; Anew = tmp;
        }
    }
    // T_ = 64 total steps (even): final state lands in A0 == d_out.
}